// Round 5
// baseline (349.046 us; speedup 1.0000x reference)
//
#include <hip/hip_runtime.h>
#include <math.h>

#define H 12
#define S 1024
#define D 128
#define NROWS (H * S) // 12288

typedef __attribute__((ext_vector_type(8))) _Float16 f16x8; // 8 fp16 in 4 VGPRs
typedef __attribute__((ext_vector_type(4))) float f32x4;
typedef __attribute__((ext_vector_type(4))) int i32x4;

__device__ __forceinline__ short f2h(float f) { // RNE float->fp16, bits as short
    _Float16 h = (_Float16)f;
    return __builtin_bit_cast(short, h);
}
__device__ __forceinline__ f16x8 fneg8(f16x8 v) { // packed sign flip
    i32x4 u = __builtin_bit_cast(i32x4, v);
    u ^= (int)0x80008000;
    return __builtin_bit_cast(f16x8, u);
}

// ---- workspace layout (BYTE offsets) ----
#define WS_QP_R   0ULL
#define WS_QP_I   6291456ULL
#define WS_KP_R   12582912ULL
#define WS_KP_I   15728640ULL
#define WS_VPT_R  18874368ULL
#define WS_VPT_I  22020096ULL
#define WS_G_R    25165824ULL
#define WS_G_I    31457280ULL
#define WS_ACAT_R 37748736ULL
#define WS_ACAT_I 50331648ULL
#define WS_LAM    62914560ULL
#define WS_SC     62914816ULL
#define W16_PER_HEAD  4194304ULL // 2*1024*1024*2B

// ============================================================
__global__ void lam_kernel(const float* __restrict__ lq1, const float* __restrict__ lk1,
                           const float* __restrict__ lq2, const float* __restrict__ lk2,
                           float* __restrict__ lam_out)
{
    int t = threadIdx.x; // 128 threads
    float p1 = lq1[t] * lk1[t];
    float p2 = lq2[t] * lk2[t];
    #pragma unroll
    for (int off = 32; off; off >>= 1) {
        p1 += __shfl_xor(p1, off);
        p2 += __shfl_xor(p2, off);
    }
    __shared__ float s1[2], s2[2];
    if ((t & 63) == 0) { s1[t >> 6] = p1; s2[t >> 6] = p2; }
    __syncthreads();
    if (t == 0) {
        float l1 = expf(s1[0] + s1[1]);
        float l2 = expf(s2[0] + s2[1]);
        float x = l1 - l2 + 0.3555090675909693f; // 0.8 - 0.6*exp(-0.3)
        lam_out[0] = 1.0f / (1.0f + expf(-x));
    }
}

// ============================================================
// Complex linear via fp16 MFMA, tile 128 rows x 64 cols, K-concat 256.
//   out_r = [xr,xi] . [wr,-wi]^T ; out_i = [xr,xi] . [wi,wr]^T
// OMODE: 0 = fp32 [row][M], 1 = fp16 [row][M], 2 = fp16 transposed [h][col][s]
// 4 waves 2x2: 64 rows x 32 cols per wave (i=4, j=2). 32 MFMA/wave/c-iter.
// ============================================================
template <int OMODE>
__global__ __launch_bounds__(256) void clin_mfma(
    const float* __restrict__ xr, const float* __restrict__ xi,
    const float* __restrict__ wr, const float* __restrict__ wi,
    const float* __restrict__ br, const float* __restrict__ bi,
    const float* __restrict__ per, const float* __restrict__ pei,
    void* __restrict__ outr_, void* __restrict__ outi_, int M)
{
    __shared__ short As[128 * 72], Brs[64 * 72], Bis[64 * 72];
    const int t = threadIdx.x;
    const int row0 = blockIdx.x * 128, col0 = blockIdx.y * 64;
    const int lane = t & 63, wid = t >> 6;
    const int wm = (wid >> 1) * 64, wn = (wid & 1) * 32;
    const int fm = lane & 15, fq = lane >> 4;
    f32x4 zero4 = {0.f, 0.f, 0.f, 0.f};
    f32x4 accr[4][2], acci[4][2];
    #pragma unroll
    for (int i = 0; i < 4; ++i)
        #pragma unroll
        for (int j = 0; j < 2; ++j) { accr[i][j] = zero4; acci[i][j] = zero4; }

    for (int c = 0; c < 4; ++c) {
        const bool hi = (c >= 2);
        const int kb = (c & 1) * 64;
        const float* Asrc = hi ? xi : xr;
        const float* Brsrc = hi ? wi : wr;
        const float* Bisrc = hi ? wr : wi;
        const float bsign = hi ? -1.0f : 1.0f;
        __syncthreads();
        #pragma unroll
        for (int it = 0; it < 8; ++it) {
            int lin = it * 256 + t;
            int r = lin >> 4, k4 = (lin & 15) * 4;
            float4 va = *(const float4*)&Asrc[(size_t)(row0 + r) * 128 + kb + k4];
            *(short4*)&As[r * 72 + k4] = make_short4(f2h(va.x), f2h(va.y), f2h(va.z), f2h(va.w));
        }
        #pragma unroll
        for (int it = 0; it < 4; ++it) {
            int lin = it * 256 + t;
            int r = lin >> 4, k4 = (lin & 15) * 4;
            float4 vr = *(const float4*)&Brsrc[(size_t)(col0 + r) * 128 + kb + k4];
            *(short4*)&Brs[r * 72 + k4] = make_short4(f2h(bsign * vr.x), f2h(bsign * vr.y),
                                                      f2h(bsign * vr.z), f2h(bsign * vr.w));
            float4 vi = *(const float4*)&Bisrc[(size_t)(col0 + r) * 128 + kb + k4];
            *(short4*)&Bis[r * 72 + k4] = make_short4(f2h(vi.x), f2h(vi.y), f2h(vi.z), f2h(vi.w));
        }
        __syncthreads();
        #pragma unroll
        for (int ks = 0; ks < 64; ks += 32) {
            f16x8 bfr[2], bfi[2];
            #pragma unroll
            for (int j = 0; j < 2; ++j) {
                bfr[j] = *(const f16x8*)&Brs[(wn + j * 16 + fm) * 72 + ks + fq * 8];
                bfi[j] = *(const f16x8*)&Bis[(wn + j * 16 + fm) * 72 + ks + fq * 8];
            }
            #pragma unroll
            for (int i = 0; i < 4; ++i) {
                f16x8 a = *(const f16x8*)&As[(wm + i * 16 + fm) * 72 + ks + fq * 8];
                #pragma unroll
                for (int j = 0; j < 2; ++j) {
                    accr[i][j] = __builtin_amdgcn_mfma_f32_16x16x32_f16(a, bfr[j], accr[i][j], 0, 0, 0);
                    acci[i][j] = __builtin_amdgcn_mfma_f32_16x16x32_f16(a, bfi[j], acci[i][j], 0, 0, 0);
                }
            }
        }
    }
    #pragma unroll
    for (int i = 0; i < 4; ++i)
        #pragma unroll
        for (int j = 0; j < 2; ++j) {
            int colc = col0 + wn + j * 16 + fm;
            float bbr = br[colc], bbi = bi[colc];
            if (OMODE == 2) {
                int rb = row0 + wm + i * 16 + fq * 4;
                int hq = rb >> 10, sq = rb & 1023;
                short4 o_r4 = make_short4(f2h(accr[i][j][0] + bbr), f2h(accr[i][j][1] + bbr),
                                          f2h(accr[i][j][2] + bbr), f2h(accr[i][j][3] + bbr));
                short4 o_i4 = make_short4(f2h(acci[i][j][0] + bbi), f2h(acci[i][j][1] + bbi),
                                          f2h(acci[i][j][2] + bbi), f2h(acci[i][j][3] + bbi));
                size_t ob = ((size_t)(hq * 128 + colc)) * 1024 + sq;
                *(short4*)&((short*)outr_)[ob] = o_r4;
                *(short4*)&((short*)outi_)[ob] = o_i4;
            } else {
                #pragma unroll
                for (int reg = 0; reg < 4; ++reg) {
                    int rr = row0 + wm + i * 16 + fq * 4 + reg;
                    float o_r = accr[i][j][reg] + bbr;
                    float o_i = acci[i][j][reg] + bbi;
                    if (per) {
                        o_r += per[(size_t)rr * 128 + (colc & 127)];
                        o_i += pei[(size_t)rr * 128 + (colc & 127)];
                    }
                    if (OMODE == 1) {
                        ((short*)outr_)[(size_t)rr * M + colc] = f2h(o_r);
                        ((short*)outi_)[(size_t)rr * M + colc] = f2h(o_i);
                    } else {
                        ((float*)outr_)[(size_t)rr * M + colc] = o_r;
                        ((float*)outi_)[(size_t)rr * M + colc] = o_i;
                    }
                }
            }
        }
}

// ============================================================
// Scores v3: 128q x 128k per block, one map. Q (both comps) staged per
// K-half and held in LDS across two B-phases (B=kr then B=ki restaged):
//   phase1: sr += qr.kr ; si += qi.kr
//   phase2: sr += qi.ki ; si += (-qr).ki
// 64 MFMA/wave per phase. mag -> fp16 w16[(hh*2+map)*S+q][k]
// ============================================================
__global__ __launch_bounds__(256) void score_mfma(
    const short* __restrict__ qp_r, const short* __restrict__ qp_i,
    const short* __restrict__ kp_r, const short* __restrict__ kp_i,
    short* __restrict__ w16, int h0)
{
    __shared__ short Qr[128 * 72], Qi[128 * 72], Kt[128 * 72];
    const int t = threadIdx.x;
    const int hh = blockIdx.z >> 1, map = blockIdx.z & 1;
    const int h = h0 + hh;
    const int q0 = blockIdx.x * 128, c0 = blockIdx.y * 128;
    const int lane = t & 63, wid = t >> 6;
    const int wm = (wid >> 1) * 64, wn = (wid & 1) * 64;
    const int fm = lane & 15, fq = lane >> 4;
    f32x4 zero4 = {0.f, 0.f, 0.f, 0.f};
    f32x4 sr[4][4], si[4][4];
    #pragma unroll
    for (int i = 0; i < 4; ++i)
        #pragma unroll
        for (int j = 0; j < 4; ++j) { sr[i][j] = zero4; si[i][j] = zero4; }

    for (int kb = 0; kb < 2; ++kb) {
        const int kbase = map * 128 + kb * 64;
        __syncthreads();
        // stage Qr, Qi (128q x 64k) and Kt = kr (128k x 64)
        #pragma unroll
        for (int it = 0; it < 8; ++it) {
            int lin = it * 256 + t;
            int r = lin >> 4, k4 = (lin & 15) * 4;
            size_t qb = (size_t)(h * S + q0 + r) * 256 + kbase + k4;
            *(short4*)&Qr[r * 72 + k4] = *(const short4*)&qp_r[qb];
            *(short4*)&Qi[r * 72 + k4] = *(const short4*)&qp_i[qb];
            *(short4*)&Kt[r * 72 + k4] =
                *(const short4*)&kp_r[(size_t)(h * S + c0 + r) * 128 + kb * 64 + k4];
        }
        __syncthreads();
        // phase 1: B = kr
        #pragma unroll
        for (int ks = 0; ks < 64; ks += 32) {
            f16x8 b[4];
            #pragma unroll
            for (int j = 0; j < 4; ++j)
                b[j] = *(const f16x8*)&Kt[(wn + j * 16 + fm) * 72 + ks + fq * 8];
            #pragma unroll
            for (int i = 0; i < 4; ++i) {
                int ao = (wm + i * 16 + fm) * 72 + ks + fq * 8;
                f16x8 ar = *(const f16x8*)&Qr[ao];
                f16x8 ai = *(const f16x8*)&Qi[ao];
                #pragma unroll
                for (int j = 0; j < 4; ++j) {
                    sr[i][j] = __builtin_amdgcn_mfma_f32_16x16x32_f16(ar, b[j], sr[i][j], 0, 0, 0);
                    si[i][j] = __builtin_amdgcn_mfma_f32_16x16x32_f16(ai, b[j], si[i][j], 0, 0, 0);
                }
            }
        }
        __syncthreads();
        // restage Kt = ki
        #pragma unroll
        for (int it = 0; it < 8; ++it) {
            int lin = it * 256 + t;
            int r = lin >> 4, k4 = (lin & 15) * 4;
            *(short4*)&Kt[r * 72 + k4] =
                *(const short4*)&kp_i[(size_t)(h * S + c0 + r) * 128 + kb * 64 + k4];
        }
        __syncthreads();
        // phase 2: B = ki ; sr += qi.ki, si += (-qr).ki
        #pragma unroll
        for (int ks = 0; ks < 64; ks += 32) {
            f16x8 b[4];
            #pragma unroll
            for (int j = 0; j < 4; ++j)
                b[j] = *(const f16x8*)&Kt[(wn + j * 16 + fm) * 72 + ks + fq * 8];
            #pragma unroll
            for (int i = 0; i < 4; ++i) {
                int ao = (wm + i * 16 + fm) * 72 + ks + fq * 8;
                f16x8 ar = *(const f16x8*)&Qr[ao];
                f16x8 ai = *(const f16x8*)&Qi[ao];
                f16x8 nr = fneg8(ar);
                #pragma unroll
                for (int j = 0; j < 4; ++j) {
                    sr[i][j] = __builtin_amdgcn_mfma_f32_16x16x32_f16(ai, b[j], sr[i][j], 0, 0, 0);
                    si[i][j] = __builtin_amdgcn_mfma_f32_16x16x32_f16(nr, b[j], si[i][j], 0, 0, 0);
                }
            }
        }
    }
    const float scale = 0.08838834764831845f;
    #pragma unroll
    for (int i = 0; i < 4; ++i)
        #pragma unroll
        for (int j = 0; j < 4; ++j) {
            int kcol = c0 + wn + j * 16 + fm;
            #pragma unroll
            for (int reg = 0; reg < 4; ++reg) {
                int q = q0 + wm + i * 16 + fq * 4 + reg;
                float r1 = sr[i][j][reg], I1 = si[i][j][reg];
                float m1 = sqrtf(fmaf(r1, r1, fmaf(I1, I1, 1e-8f))) * scale;
                w16[(((size_t)hh * 2 + map) * S + q) * S + kcol] = f2h(m1);
            }
        }
}

// ============================================================
// Row softmax over 1024, fp16 in/out in place, fp32 math. One block/row.
// ============================================================
__global__ __launch_bounds__(256) void softmax_f16(short* __restrict__ w16)
{
    short* row = w16 + (size_t)blockIdx.x * S;
    int t = threadIdx.x;
    short4 s = ((short4*)row)[t];
    float f0 = (float)__builtin_bit_cast(_Float16, s.x);
    float f1 = (float)__builtin_bit_cast(_Float16, s.y);
    float f2v = (float)__builtin_bit_cast(_Float16, s.z);
    float f3 = (float)__builtin_bit_cast(_Float16, s.w);
    float m = fmaxf(fmaxf(f0, f1), fmaxf(f2v, f3));
    #pragma unroll
    for (int off = 32; off; off >>= 1) m = fmaxf(m, __shfl_xor(m, off));
    __shared__ float redm[4], reds[4];
    int w = t >> 6;
    if ((t & 63) == 0) redm[w] = m;
    __syncthreads();
    m = fmaxf(fmaxf(redm[0], redm[1]), fmaxf(redm[2], redm[3]));
    float e0 = __expf(f0 - m), e1 = __expf(f1 - m), e2 = __expf(f2v - m), e3 = __expf(f3 - m);
    float ssum = e0 + e1 + e2 + e3;
    #pragma unroll
    for (int off = 32; off; off >>= 1) ssum += __shfl_xor(ssum, off);
    if ((t & 63) == 0) reds[w] = ssum;
    __syncthreads();
    ssum = reds[0] + reds[1] + reds[2] + reds[3];
    float inv = 1.0f / ssum;
    s.x = f2h(e0 * inv); s.y = f2h(e1 * inv); s.z = f2h(e2 * inv); s.w = f2h(e3 * inv);
    ((short4*)row)[t] = s;
}

// ============================================================
// AV v2: 64q x full 128d, both maps, ONE complex component per block
// (blockIdx.y = 0:r, 1:i). W tiles shared by both maps. V from vpT[h][d][s].
// 4 waves 2x2: 32q x 64d per wave (i=2, j=4). 32 MFMA/wave per k-chunk.
// ============================================================
__global__ __launch_bounds__(256) void av_mfma(
    const short* __restrict__ w16, const short* __restrict__ vpT_r, const short* __restrict__ vpT_i,
    float* __restrict__ acat_r, float* __restrict__ acat_i, int h0)
{
    __shared__ short W1[64 * 72], W2[64 * 72], Vc[128 * 72];
    const int t = threadIdx.x;
    const int hh = blockIdx.z, h = h0 + hh;
    const int comp = blockIdx.y;
    const int q0 = blockIdx.x * 64;
    const short* vpT = comp ? vpT_i : vpT_r;
    float* acat = comp ? acat_i : acat_r;
    const int lane = t & 63, wid = t >> 6;
    const int wm = (wid >> 1) * 32, wn = (wid & 1) * 64;
    const int fm = lane & 15, fq = lane >> 4;
    f32x4 zero4 = {0.f, 0.f, 0.f, 0.f};
    f32x4 a1[2][4], a2[2][4];
    #pragma unroll
    for (int i = 0; i < 2; ++i)
        #pragma unroll
        for (int j = 0; j < 4; ++j) { a1[i][j] = zero4; a2[i][j] = zero4; }

    for (int k0 = 0; k0 < S; k0 += 64) {
        __syncthreads();
        #pragma unroll
        for (int it = 0; it < 4; ++it) {
            int lin = it * 256 + t;
            int r = lin >> 4, k4 = (lin & 15) * 4;
            *(short4*)&W1[r * 72 + k4] = *(const short4*)&w16[(((size_t)hh * 2 + 0) * S + q0 + r) * S + k0 + k4];
            *(short4*)&W2[r * 72 + k4] = *(const short4*)&w16[(((size_t)hh * 2 + 1) * S + q0 + r) * S + k0 + k4];
        }
        #pragma unroll
        for (int it = 0; it < 8; ++it) {
            int lin = it * 256 + t;
            int dd = lin >> 4, k4 = (lin & 15) * 4;
            *(short4*)&Vc[dd * 72 + k4] = *(const short4*)&vpT[(size_t)(h * 128 + dd) * 1024 + k0 + k4];
        }
        __syncthreads();
        #pragma unroll
        for (int ks = 0; ks < 64; ks += 32) {
            f16x8 b[4];
            #pragma unroll
            for (int j = 0; j < 4; ++j)
                b[j] = *(const f16x8*)&Vc[(wn + j * 16 + fm) * 72 + ks + fq * 8];
            #pragma unroll
            for (int i = 0; i < 2; ++i) {
                int wo = (wm + i * 16 + fm) * 72 + ks + fq * 8;
                f16x8 w1f = *(const f16x8*)&W1[wo];
                f16x8 w2f = *(const f16x8*)&W2[wo];
                #pragma unroll
                for (int j = 0; j < 4; ++j) {
                    a1[i][j] = __builtin_amdgcn_mfma_f32_16x16x32_f16(w1f, b[j], a1[i][j], 0, 0, 0);
                    a2[i][j] = __builtin_amdgcn_mfma_f32_16x16x32_f16(w2f, b[j], a2[i][j], 0, 0, 0);
                }
            }
        }
    }
    #pragma unroll
    for (int i = 0; i < 2; ++i)
        #pragma unroll
        for (int j = 0; j < 4; ++j) {
            int d = wn + j * 16 + fm;
            #pragma unroll
            for (int reg = 0; reg < 4; ++reg) {
                int q = q0 + wm + i * 16 + fq * 4 + reg;
                size_t rowb = (size_t)(h * S + q) * 256;
                acat[rowb + d]       = a1[i][j][reg];
                acat[rowb + 128 + d] = a2[i][j][reg];
            }
        }
}

// ============================================================
// RMS over 256 complex + sub_w + (a1 - lam*a2) + complex gate (in place g).
// ============================================================
__global__ __launch_bounds__(256) void rmsgate_kernel(
    const float* __restrict__ acat_r, const float* __restrict__ acat_i,
    const float* __restrict__ sub_w, const float* __restrict__ lam_ptr,
    float* __restrict__ g_r, float* __restrict__ g_i)
{
    int row = blockIdx.x;
    int t = threadIdx.x;
    float ar = acat_r[(size_t)row * 256 + t];
    float ai = acat_i[(size_t)row * 256 + t];
    float ss = fmaf(ar, ar, ai * ai);
    #pragma unroll
    for (int off = 32; off; off >>= 1) ss += __shfl_xor(ss, off);
    __shared__ float red[4];
    if ((t & 63) == 0) red[t >> 6] = ss;
    __syncthreads();
    float total = red[0] + red[1] + red[2] + red[3];
    float inv_rms = 1.0f / sqrtf(total * (1.0f / 256.0f) + 1e-5f);
    float sw = sub_w[t];
    __shared__ float Cr[256], Ci[256];
    Cr[t] = ar * inv_rms * sw;
    Ci[t] = ai * inv_rms * sw;
    __syncthreads();
    if (t < 128) {
        float lam = lam_ptr[0];
        float o_r = Cr[t] - lam * Cr[t + 128];
        float o_i = Ci[t] - lam * Ci[t + 128];
        float gr = g_r[(size_t)row * 128 + t];
        float gi = g_i[(size_t)row * 128 + t];
        g_r[(size_t)row * 128 + t] = gr * o_r - gi * o_i;
        g_i[(size_t)row * 128 + t] = gr * o_i + gi * o_r;
    }
}

// ============================================================
extern "C" void kernel_launch(void* const* d_in, const int* in_sizes, int n_in,
                              void* d_out, int out_size, void* d_ws, size_t ws_size,
                              hipStream_t stream)
{
    (void)in_sizes; (void)n_in; (void)out_size;
    const float* q_r    = (const float*)d_in[0];
    const float* q_i    = (const float*)d_in[1];
    const float* k_r    = (const float*)d_in[2];
    const float* k_i    = (const float*)d_in[3];
    const float* v_r    = (const float*)d_in[4];
    const float* v_i    = (const float*)d_in[5];
    const float* pe_q_r = (const float*)d_in[6];
    const float* pe_q_i = (const float*)d_in[7];
    const float* pe_k_r = (const float*)d_in[8];
    const float* pe_k_i = (const float*)d_in[9];
    const float* qw_r   = (const float*)d_in[10];
    const float* qw_i   = (const float*)d_in[11];
    const float* qb_r   = (const float*)d_in[12];
    const float* qb_i   = (const float*)d_in[13];
    const float* kw_r   = (const float*)d_in[14];
    const float* kw_i   = (const float*)d_in[15];
    const float* kb_r   = (const float*)d_in[16];
    const float* kb_i   = (const float*)d_in[17];
    const float* vw_r   = (const float*)d_in[18];
    const float* vw_i   = (const float*)d_in[19];
    const float* vb_r   = (const float*)d_in[20];
    const float* vb_i   = (const float*)d_in[21];
    const float* gw_r   = (const float*)d_in[22];
    const float* gw_i   = (const float*)d_in[23];
    const float* gb_r   = (const float*)d_in[24];
    const float* gb_i   = (const float*)d_in[25];
    const float* ow_r   = (const float*)d_in[26];
    const float* ow_i   = (const float*)d_in[27];
    const float* ob_r   = (const float*)d_in[28];
    const float* ob_i   = (const float*)d_in[29];
    const float* lq1    = (const float*)d_in[30];
    const float* lk1    = (const float*)d_in[31];
    const float* lq2    = (const float*)d_in[32];
    const float* lk2    = (const float*)d_in[33];
    const float* sub_w  = (const float*)d_in[34];

    char* ws = (char*)d_ws;
    short* qp_r   = (short*)(ws + WS_QP_R);
    short* qp_i   = (short*)(ws + WS_QP_I);
    short* kp_r   = (short*)(ws + WS_KP_R);
    short* kp_i   = (short*)(ws + WS_KP_I);
    short* vpT_r  = (short*)(ws + WS_VPT_R);
    short* vpT_i  = (short*)(ws + WS_VPT_I);
    float* g_r    = (float*)(ws + WS_G_R);
    float* g_i    = (float*)(ws + WS_G_I);
    float* acat_r = (float*)(ws + WS_ACAT_R);
    float* acat_i = (float*)(ws + WS_ACAT_I);
    float* lam    = (float*)(ws + WS_LAM);
    short* w16    = (short*)(ws + WS_SC);

    float* out_r = (float*)d_out;
    float* out_i = out_r + (size_t)NROWS * D;

    // head-chunking by workspace (depends only on ws_size -> graph-safe)
    size_t avail = ws_size > WS_SC ? ws_size - WS_SC : 0;
    int nh_chunk = (int)(avail / W16_PER_HEAD);
    if (nh_chunk < 1) nh_chunk = 1;
    if (nh_chunk > H) nh_chunk = H;

    lam_kernel<<<1, 128, 0, stream>>>(lq1, lk1, lq2, lk2, lam);

    // projections (q/k -> fp16 with PE folded; v -> fp16 transposed; g -> fp32)
    clin_mfma<1><<<dim3(96, 4), 256, 0, stream>>>(q_r, q_i, qw_r, qw_i, qb_r, qb_i,
                                                  pe_q_r, pe_q_i, qp_r, qp_i, 256);
    clin_mfma<1><<<dim3(96, 2), 256, 0, stream>>>(k_r, k_i, kw_r, kw_i, kb_r, kb_i,
                                                  pe_k_r, pe_k_i, kp_r, kp_i, 128);
    clin_mfma<2><<<dim3(96, 2), 256, 0, stream>>>(v_r, v_i, vw_r, vw_i, vb_r, vb_i,
                                                  nullptr, nullptr, vpT_r, vpT_i, 128);
    clin_mfma<0><<<dim3(96, 2), 256, 0, stream>>>(q_r, q_i, gw_r, gw_i, gb_r, gb_i,
                                                  nullptr, nullptr, g_r, g_i, 128);

    for (int h0 = 0; h0 < H; h0 += nh_chunk) {
        int nhh = (H - h0 < nh_chunk) ? (H - h0) : nh_chunk;
        score_mfma<<<dim3(8, 8, nhh * 2), 256, 0, stream>>>(qp_r, qp_i, kp_r, kp_i, w16, h0);
        softmax_f16<<<nhh * 2 * S, 256, 0, stream>>>(w16);
        av_mfma<<<dim3(16, 2, nhh), 256, 0, stream>>>(w16, vpT_r, vpT_i, acat_r, acat_i, h0);
    }

    rmsgate_kernel<<<NROWS, 256, 0, stream>>>(acat_r, acat_i, sub_w, lam, g_r, g_i);

    clin_mfma<0><<<dim3(96, 2), 256, 0, stream>>>(g_r, g_i, ow_r, ow_i, ob_r, ob_i,
                                                  nullptr, nullptr, out_r, out_i, 128);
}

// Round 6
// 318.277 us; speedup vs baseline: 1.0967x; 1.0967x over previous
//
#include <hip/hip_runtime.h>
#include <math.h>

#define H 12
#define S 1024
#define D 128
#define NROWS (H * S) // 12288

typedef __attribute__((ext_vector_type(8))) _Float16 f16x8; // 8 fp16 in 4 VGPRs
typedef __attribute__((ext_vector_type(4))) float f32x4;
typedef __attribute__((ext_vector_type(4))) int i32x4;

__device__ __forceinline__ short f2h(float f) { // RNE float->fp16, bits as short
    _Float16 h = (_Float16)f;
    return __builtin_bit_cast(short, h);
}
__device__ __forceinline__ f16x8 fneg8(f16x8 v) { // packed sign flip
    i32x4 u = __builtin_bit_cast(i32x4, v);
    u ^= (int)0x80008000;
    return __builtin_bit_cast(f16x8, u);
}

// ---- workspace layout (BYTE offsets) ----
#define WS_QP_R   0ULL
#define WS_QP_I   6291456ULL
#define WS_KP_R   12582912ULL
#define WS_KP_I   15728640ULL
#define WS_VPT_R  18874368ULL
#define WS_VPT_I  22020096ULL
#define WS_G_R    25165824ULL
#define WS_G_I    31457280ULL
#define WS_ACAT_R 37748736ULL
#define WS_ACAT_I 50331648ULL
#define WS_LAM    62914560ULL
#define WS_SC     62914816ULL
#define W16_PER_HEAD  4194304ULL // 2*1024*1024*2B

// ============================================================
__global__ void lam_kernel(const float* __restrict__ lq1, const float* __restrict__ lk1,
                           const float* __restrict__ lq2, const float* __restrict__ lk2,
                           float* __restrict__ lam_out)
{
    int t = threadIdx.x; // 128 threads
    float p1 = lq1[t] * lk1[t];
    float p2 = lq2[t] * lk2[t];
    #pragma unroll
    for (int off = 32; off; off >>= 1) {
        p1 += __shfl_xor(p1, off);
        p2 += __shfl_xor(p2, off);
    }
    __shared__ float s1[2], s2[2];
    if ((t & 63) == 0) { s1[t >> 6] = p1; s2[t >> 6] = p2; }
    __syncthreads();
    if (t == 0) {
        float l1 = expf(s1[0] + s1[1]);
        float l2 = expf(s2[0] + s2[1]);
        float x = l1 - l2 + 0.3555090675909693f; // 0.8 - 0.6*exp(-0.3)
        lam_out[0] = 1.0f / (1.0f + expf(-x));
    }
}

// ============================================================
// ALL FOUR projections in ONE dispatch. grid = (96, 10):
//  y 0-3: q-proj  (M=256, fp16 out, +pe_q)       col0 = y*64
//  y 4-5: k-proj  (M=128, fp16 out, +pe_k)       col0 = (y-4)*64
//  y 6-7: v-proj  (M=128, fp16 transposed out)   col0 = (y-6)*64
//  y 8-9: g-proj  (M=128, fp32 out)              col0 = (y-8)*64
// Tile 128 rows x 64 cols, K-concat 256 (complex fold):
//   out_r = [xr,xi].[wr,-wi]^T ; out_i = [xr,xi].[wi,wr]^T
// 4 waves 2x2: 64 rows x 32 cols per wave (i=4, j=2).
// ============================================================
__global__ __launch_bounds__(256) void proj_all(
    const float* __restrict__ q_r, const float* __restrict__ q_i,
    const float* __restrict__ k_r, const float* __restrict__ k_i,
    const float* __restrict__ v_r, const float* __restrict__ v_i,
    const float* __restrict__ pe_q_r, const float* __restrict__ pe_q_i,
    const float* __restrict__ pe_k_r, const float* __restrict__ pe_k_i,
    const float* __restrict__ qw_r, const float* __restrict__ qw_i,
    const float* __restrict__ qb_r, const float* __restrict__ qb_i,
    const float* __restrict__ kw_r, const float* __restrict__ kw_i,
    const float* __restrict__ kb_r, const float* __restrict__ kb_i,
    const float* __restrict__ vw_r, const float* __restrict__ vw_i,
    const float* __restrict__ vb_r, const float* __restrict__ vb_i,
    const float* __restrict__ gw_r, const float* __restrict__ gw_i,
    const float* __restrict__ gb_r, const float* __restrict__ gb_i,
    short* __restrict__ qp_r, short* __restrict__ qp_i,
    short* __restrict__ kp_r, short* __restrict__ kp_i,
    short* __restrict__ vpT_r, short* __restrict__ vpT_i,
    float* __restrict__ g_r, float* __restrict__ g_i)
{
    const int y = blockIdx.y;
    const float *xr, *xi, *wr, *wi, *br, *bi, *per = nullptr, *pei = nullptr;
    void *outr_, *outi_;
    int M, omode, col0;
    if (y < 4)      { xr = q_r; xi = q_i; wr = qw_r; wi = qw_i; br = qb_r; bi = qb_i;
                      per = pe_q_r; pei = pe_q_i; outr_ = qp_r; outi_ = qp_i;
                      M = 256; omode = 1; col0 = y * 64; }
    else if (y < 6) { xr = k_r; xi = k_i; wr = kw_r; wi = kw_i; br = kb_r; bi = kb_i;
                      per = pe_k_r; pei = pe_k_i; outr_ = kp_r; outi_ = kp_i;
                      M = 128; omode = 1; col0 = (y - 4) * 64; }
    else if (y < 8) { xr = v_r; xi = v_i; wr = vw_r; wi = vw_i; br = vb_r; bi = vb_i;
                      outr_ = vpT_r; outi_ = vpT_i;
                      M = 128; omode = 2; col0 = (y - 6) * 64; }
    else            { xr = q_r; xi = q_i; wr = gw_r; wi = gw_i; br = gb_r; bi = gb_i;
                      outr_ = g_r; outi_ = g_i;
                      M = 128; omode = 0; col0 = (y - 8) * 64; }

    __shared__ short As[128 * 72], Brs[64 * 72], Bis[64 * 72];
    const int t = threadIdx.x;
    const int row0 = blockIdx.x * 128;
    const int lane = t & 63, wid = t >> 6;
    const int wm = (wid >> 1) * 64, wn = (wid & 1) * 32;
    const int fm = lane & 15, fq = lane >> 4;
    f32x4 zero4 = {0.f, 0.f, 0.f, 0.f};
    f32x4 accr[4][2], acci[4][2];
    #pragma unroll
    for (int i = 0; i < 4; ++i)
        #pragma unroll
        for (int j = 0; j < 2; ++j) { accr[i][j] = zero4; acci[i][j] = zero4; }

    for (int c = 0; c < 4; ++c) {
        const bool hi = (c >= 2);
        const int kb = (c & 1) * 64;
        const float* Asrc = hi ? xi : xr;
        const float* Brsrc = hi ? wi : wr;
        const float* Bisrc = hi ? wr : wi;
        const float bsign = hi ? -1.0f : 1.0f;
        __syncthreads();
        #pragma unroll
        for (int it = 0; it < 8; ++it) {
            int lin = it * 256 + t;
            int r = lin >> 4, k4 = (lin & 15) * 4;
            float4 va = *(const float4*)&Asrc[(size_t)(row0 + r) * 128 + kb + k4];
            *(short4*)&As[r * 72 + k4] = make_short4(f2h(va.x), f2h(va.y), f2h(va.z), f2h(va.w));
        }
        #pragma unroll
        for (int it = 0; it < 4; ++it) {
            int lin = it * 256 + t;
            int r = lin >> 4, k4 = (lin & 15) * 4;
            float4 vr = *(const float4*)&Brsrc[(size_t)(col0 + r) * 128 + kb + k4];
            *(short4*)&Brs[r * 72 + k4] = make_short4(f2h(bsign * vr.x), f2h(bsign * vr.y),
                                                      f2h(bsign * vr.z), f2h(bsign * vr.w));
            float4 vi = *(const float4*)&Bisrc[(size_t)(col0 + r) * 128 + kb + k4];
            *(short4*)&Bis[r * 72 + k4] = make_short4(f2h(vi.x), f2h(vi.y), f2h(vi.z), f2h(vi.w));
        }
        __syncthreads();
        #pragma unroll
        for (int ks = 0; ks < 64; ks += 32) {
            f16x8 bfr[2], bfi[2];
            #pragma unroll
            for (int j = 0; j < 2; ++j) {
                bfr[j] = *(const f16x8*)&Brs[(wn + j * 16 + fm) * 72 + ks + fq * 8];
                bfi[j] = *(const f16x8*)&Bis[(wn + j * 16 + fm) * 72 + ks + fq * 8];
            }
            #pragma unroll
            for (int i = 0; i < 4; ++i) {
                f16x8 a = *(const f16x8*)&As[(wm + i * 16 + fm) * 72 + ks + fq * 8];
                #pragma unroll
                for (int j = 0; j < 2; ++j) {
                    accr[i][j] = __builtin_amdgcn_mfma_f32_16x16x32_f16(a, bfr[j], accr[i][j], 0, 0, 0);
                    acci[i][j] = __builtin_amdgcn_mfma_f32_16x16x32_f16(a, bfi[j], acci[i][j], 0, 0, 0);
                }
            }
        }
    }
    #pragma unroll
    for (int i = 0; i < 4; ++i)
        #pragma unroll
        for (int j = 0; j < 2; ++j) {
            int colc = col0 + wn + j * 16 + fm;
            float bbr = br[colc], bbi = bi[colc];
            if (omode == 2) {
                int rb = row0 + wm + i * 16 + fq * 4;
                int hq = rb >> 10, sq = rb & 1023;
                short4 o_r4 = make_short4(f2h(accr[i][j][0] + bbr), f2h(accr[i][j][1] + bbr),
                                          f2h(accr[i][j][2] + bbr), f2h(accr[i][j][3] + bbr));
                short4 o_i4 = make_short4(f2h(acci[i][j][0] + bbi), f2h(acci[i][j][1] + bbi),
                                          f2h(acci[i][j][2] + bbi), f2h(acci[i][j][3] + bbi));
                size_t ob = ((size_t)(hq * 128 + colc)) * 1024 + sq;
                *(short4*)&((short*)outr_)[ob] = o_r4;
                *(short4*)&((short*)outi_)[ob] = o_i4;
            } else {
                #pragma unroll
                for (int reg = 0; reg < 4; ++reg) {
                    int rr = row0 + wm + i * 16 + fq * 4 + reg;
                    float o_r = accr[i][j][reg] + bbr;
                    float o_i = acci[i][j][reg] + bbi;
                    if (per) {
                        o_r += per[(size_t)rr * 128 + (colc & 127)];
                        o_i += pei[(size_t)rr * 128 + (colc & 127)];
                    }
                    if (omode == 1) {
                        ((short*)outr_)[(size_t)rr * M + colc] = f2h(o_r);
                        ((short*)outi_)[(size_t)rr * M + colc] = f2h(o_i);
                    } else {
                        ((float*)outr_)[(size_t)rr * M + colc] = o_r;
                        ((float*)outi_)[(size_t)rr * M + colc] = o_i;
                    }
                }
            }
        }
}

// ============================================================
// o-projection (separate: depends on rmsgate). Same 128x64 tile, fp32 in/out.
// ============================================================
__global__ __launch_bounds__(256) void oproj_mfma(
    const float* __restrict__ xr, const float* __restrict__ xi,
    const float* __restrict__ wr, const float* __restrict__ wi,
    const float* __restrict__ br, const float* __restrict__ bi,
    float* __restrict__ outr, float* __restrict__ outi)
{
    __shared__ short As[128 * 72], Brs[64 * 72], Bis[64 * 72];
    const int t = threadIdx.x;
    const int row0 = blockIdx.x * 128, col0 = blockIdx.y * 64;
    const int lane = t & 63, wid = t >> 6;
    const int wm = (wid >> 1) * 64, wn = (wid & 1) * 32;
    const int fm = lane & 15, fq = lane >> 4;
    f32x4 zero4 = {0.f, 0.f, 0.f, 0.f};
    f32x4 accr[4][2], acci[4][2];
    #pragma unroll
    for (int i = 0; i < 4; ++i)
        #pragma unroll
        for (int j = 0; j < 2; ++j) { accr[i][j] = zero4; acci[i][j] = zero4; }

    for (int c = 0; c < 4; ++c) {
        const bool hi = (c >= 2);
        const int kb = (c & 1) * 64;
        const float* Asrc = hi ? xi : xr;
        const float* Brsrc = hi ? wi : wr;
        const float* Bisrc = hi ? wr : wi;
        const float bsign = hi ? -1.0f : 1.0f;
        __syncthreads();
        #pragma unroll
        for (int it = 0; it < 8; ++it) {
            int lin = it * 256 + t;
            int r = lin >> 4, k4 = (lin & 15) * 4;
            float4 va = *(const float4*)&Asrc[(size_t)(row0 + r) * 128 + kb + k4];
            *(short4*)&As[r * 72 + k4] = make_short4(f2h(va.x), f2h(va.y), f2h(va.z), f2h(va.w));
        }
        #pragma unroll
        for (int it = 0; it < 4; ++it) {
            int lin = it * 256 + t;
            int r = lin >> 4, k4 = (lin & 15) * 4;
            float4 vr = *(const float4*)&Brsrc[(size_t)(col0 + r) * 128 + kb + k4];
            *(short4*)&Brs[r * 72 + k4] = make_short4(f2h(bsign * vr.x), f2h(bsign * vr.y),
                                                      f2h(bsign * vr.z), f2h(bsign * vr.w));
            float4 vi = *(const float4*)&Bisrc[(size_t)(col0 + r) * 128 + kb + k4];
            *(short4*)&Bis[r * 72 + k4] = make_short4(f2h(vi.x), f2h(vi.y), f2h(vi.z), f2h(vi.w));
        }
        __syncthreads();
        #pragma unroll
        for (int ks = 0; ks < 64; ks += 32) {
            f16x8 bfr[2], bfi[2];
            #pragma unroll
            for (int j = 0; j < 2; ++j) {
                bfr[j] = *(const f16x8*)&Brs[(wn + j * 16 + fm) * 72 + ks + fq * 8];
                bfi[j] = *(const f16x8*)&Bis[(wn + j * 16 + fm) * 72 + ks + fq * 8];
            }
            #pragma unroll
            for (int i = 0; i < 4; ++i) {
                f16x8 a = *(const f16x8*)&As[(wm + i * 16 + fm) * 72 + ks + fq * 8];
                #pragma unroll
                for (int j = 0; j < 2; ++j) {
                    accr[i][j] = __builtin_amdgcn_mfma_f32_16x16x32_f16(a, bfr[j], accr[i][j], 0, 0, 0);
                    acci[i][j] = __builtin_amdgcn_mfma_f32_16x16x32_f16(a, bfi[j], acci[i][j], 0, 0, 0);
                }
            }
        }
    }
    #pragma unroll
    for (int i = 0; i < 4; ++i)
        #pragma unroll
        for (int j = 0; j < 2; ++j) {
            int colc = col0 + wn + j * 16 + fm;
            float bbr = br[colc], bbi = bi[colc];
            #pragma unroll
            for (int reg = 0; reg < 4; ++reg) {
                int rr = row0 + wm + i * 16 + fq * 4 + reg;
                outr[(size_t)rr * 128 + colc] = accr[i][j][reg] + bbr;
                outi[(size_t)rr * 128 + colc] = acci[i][j][reg] + bbi;
            }
        }
}

// ============================================================
// Scores (r4 config): one map per block, 64q x 128k tile, K-chunk 64.
// A-fragments (q_r, q_i) held in regs across two B-phases (kr, then ki):
//   phase1: sr += qr.kr ; si += qi.kr
//   phase2: sr += qi.ki ; si += (-qr).ki
// mag = sqrt(sr^2+si^2+1e-8)*D^-.5 -> fp16 w16[(hh*2+map)*S+q][k]
// 36KB LDS, ~108 VGPR -> high residency (this beat the 128x128 variant).
// ============================================================
__global__ __launch_bounds__(256) void score_mfma(
    const short* __restrict__ qp_r, const short* __restrict__ qp_i,
    const short* __restrict__ kp_r, const short* __restrict__ kp_i,
    short* __restrict__ w16, int h0)
{
    __shared__ short Qr[64 * 72], Qi[64 * 72], Kt[128 * 72];
    const int t = threadIdx.x;
    const int hh = blockIdx.z >> 1, map = blockIdx.z & 1;
    const int h = h0 + hh;
    const int q0 = blockIdx.x * 64, c0 = blockIdx.y * 128;
    const int lane = t & 63, wid = t >> 6;
    const int wm = (wid >> 1) * 32, wn = (wid & 1) * 64;
    const int fm = lane & 15, fq = lane >> 4;
    f32x4 zero4 = {0.f, 0.f, 0.f, 0.f};
    f32x4 sr[2][4], si[2][4];
    #pragma unroll
    for (int i = 0; i < 2; ++i)
        #pragma unroll
        for (int j = 0; j < 4; ++j) { sr[i][j] = zero4; si[i][j] = zero4; }

    for (int kb = 0; kb < 2; ++kb) {
        const int kbase = map * 128 + kb * 64;
        __syncthreads();
        // stage Qr, Qi (64x64) and Kt = kr (128x64)
        #pragma unroll
        for (int i = 0; i < 4; ++i) {
            int lin = i * 256 + t;
            int r = lin >> 4, k4 = (lin & 15) * 4;
            size_t qb = (size_t)(h * S + q0 + r) * 256 + kbase + k4;
            *(short4*)&Qr[r * 72 + k4] = *(const short4*)&qp_r[qb];
            *(short4*)&Qi[r * 72 + k4] = *(const short4*)&qp_i[qb];
        }
        #pragma unroll
        for (int i = 0; i < 8; ++i) {
            int lin = i * 256 + t;
            int r = lin >> 4, k4 = (lin & 15) * 4;
            *(short4*)&Kt[r * 72 + k4] =
                *(const short4*)&kp_r[(size_t)(h * S + c0 + r) * 128 + kb * 64 + k4];
        }
        __syncthreads();
        // load A fragments (held across both phases)
        f16x8 aR[2][2], aI[2][2]; // [ks][i]
        #pragma unroll
        for (int ks = 0; ks < 2; ++ks)
            #pragma unroll
            for (int i = 0; i < 2; ++i) {
                int ao = (wm + i * 16 + fm) * 72 + ks * 32 + fq * 8;
                aR[ks][i] = *(const f16x8*)&Qr[ao];
                aI[ks][i] = *(const f16x8*)&Qi[ao];
            }
        // phase 1: B = kr
        #pragma unroll
        for (int ks = 0; ks < 2; ++ks) {
            f16x8 b[4];
            #pragma unroll
            for (int j = 0; j < 4; ++j)
                b[j] = *(const f16x8*)&Kt[(wn + j * 16 + fm) * 72 + ks * 32 + fq * 8];
            #pragma unroll
            for (int i = 0; i < 2; ++i)
                #pragma unroll
                for (int j = 0; j < 4; ++j) {
                    sr[i][j] = __builtin_amdgcn_mfma_f32_16x16x32_f16(aR[ks][i], b[j], sr[i][j], 0, 0, 0);
                    si[i][j] = __builtin_amdgcn_mfma_f32_16x16x32_f16(aI[ks][i], b[j], si[i][j], 0, 0, 0);
                }
        }
        __syncthreads();
        // restage Kt = ki
        #pragma unroll
        for (int i = 0; i < 8; ++i) {
            int lin = i * 256 + t;
            int r = lin >> 4, k4 = (lin & 15) * 4;
            *(short4*)&Kt[r * 72 + k4] =
                *(const short4*)&kp_i[(size_t)(h * S + c0 + r) * 128 + kb * 64 + k4];
        }
        __syncthreads();
        // phase 2: B = ki ; sr += qi.ki, si += (-qr).ki
        #pragma unroll
        for (int ks = 0; ks < 2; ++ks) {
            f16x8 b[4];
            #pragma unroll
            for (int j = 0; j < 4; ++j)
                b[j] = *(const f16x8*)&Kt[(wn + j * 16 + fm) * 72 + ks * 32 + fq * 8];
            f16x8 nR0 = fneg8(aR[ks][0]), nR1 = fneg8(aR[ks][1]);
            #pragma unroll
            for (int j = 0; j < 4; ++j) {
                sr[0][j] = __builtin_amdgcn_mfma_f32_16x16x32_f16(aI[ks][0], b[j], sr[0][j], 0, 0, 0);
                si[0][j] = __builtin_amdgcn_mfma_f32_16x16x32_f16(nR0, b[j], si[0][j], 0, 0, 0);
                sr[1][j] = __builtin_amdgcn_mfma_f32_16x16x32_f16(aI[ks][1], b[j], sr[1][j], 0, 0, 0);
                si[1][j] = __builtin_amdgcn_mfma_f32_16x16x32_f16(nR1, b[j], si[1][j], 0, 0, 0);
            }
        }
    }
    const float scale = 0.08838834764831845f;
    #pragma unroll
    for (int i = 0; i < 2; ++i)
        #pragma unroll
        for (int j = 0; j < 4; ++j) {
            int kcol = c0 + wn + j * 16 + fm;
            #pragma unroll
            for (int reg = 0; reg < 4; ++reg) {
                int q = q0 + wm + i * 16 + fq * 4 + reg;
                float r1 = sr[i][j][reg], I1 = si[i][j][reg];
                float m1 = sqrtf(fmaf(r1, r1, fmaf(I1, I1, 1e-8f))) * scale;
                w16[(((size_t)hh * 2 + map) * S + q) * S + kcol] = f2h(m1);
            }
        }
}

// ============================================================
// Row softmax over 1024, fp16 in/out in place, fp32 math. One block/row.
// ============================================================
__global__ __launch_bounds__(256) void softmax_f16(short* __restrict__ w16)
{
    short* row = w16 + (size_t)blockIdx.x * S;
    int t = threadIdx.x;
    short4 s = ((short4*)row)[t];
    float f0 = (float)__builtin_bit_cast(_Float16, s.x);
    float f1 = (float)__builtin_bit_cast(_Float16, s.y);
    float f2v = (float)__builtin_bit_cast(_Float16, s.z);
    float f3 = (float)__builtin_bit_cast(_Float16, s.w);
    float m = fmaxf(fmaxf(f0, f1), fmaxf(f2v, f3));
    #pragma unroll
    for (int off = 32; off; off >>= 1) m = fmaxf(m, __shfl_xor(m, off));
    __shared__ float redm[4], reds[4];
    int w = t >> 6;
    if ((t & 63) == 0) redm[w] = m;
    __syncthreads();
    m = fmaxf(fmaxf(redm[0], redm[1]), fmaxf(redm[2], redm[3]));
    float e0 = __expf(f0 - m), e1 = __expf(f1 - m), e2 = __expf(f2v - m), e3 = __expf(f3 - m);
    float ssum = e0 + e1 + e2 + e3;
    #pragma unroll
    for (int off = 32; off; off >>= 1) ssum += __shfl_xor(ssum, off);
    if ((t & 63) == 0) reds[w] = ssum;
    __syncthreads();
    ssum = reds[0] + reds[1] + reds[2] + reds[3];
    float inv = 1.0f / ssum;
    s.x = f2h(e0 * inv); s.y = f2h(e1 * inv); s.z = f2h(e2 * inv); s.w = f2h(e3 * inv);
    ((short4*)row)[t] = s;
}

// ============================================================
// AV: 64q x full 128d, both maps, ONE complex component per block
// (blockIdx.y = 0:r, 1:i). W tiles shared by both maps. V from vpT[h][d][s].
// ============================================================
__global__ __launch_bounds__(256) void av_mfma(
    const short* __restrict__ w16, const short* __restrict__ vpT_r, const short* __restrict__ vpT_i,
    float* __restrict__ acat_r, float* __restrict__ acat_i, int h0)
{
    __shared__ short W1[64 * 72], W2[64 * 72], Vc[128 * 72];
    const int t = threadIdx.x;
    const int hh = blockIdx.z, h = h0 + hh;
    const int comp = blockIdx.y;
    const int q0 = blockIdx.x * 64;
    const short* vpT = comp ? vpT_i : vpT_r;
    float* acat = comp ? acat_i : acat_r;
    const int lane = t & 63, wid = t >> 6;
    const int wm = (wid >> 1) * 32, wn = (wid & 1) * 64;
    const int fm = lane & 15, fq = lane >> 4;
    f32x4 zero4 = {0.f, 0.f, 0.f, 0.f};
    f32x4 a1[2][4], a2[2][4];
    #pragma unroll
    for (int i = 0; i < 2; ++i)
        #pragma unroll
        for (int j = 0; j < 4; ++j) { a1[i][j] = zero4; a2[i][j] = zero4; }

    for (int k0 = 0; k0 < S; k0 += 64) {
        __syncthreads();
        #pragma unroll
        for (int it = 0; it < 4; ++it) {
            int lin = it * 256 + t;
            int r = lin >> 4, k4 = (lin & 15) * 4;
            *(short4*)&W1[r * 72 + k4] = *(const short4*)&w16[(((size_t)hh * 2 + 0) * S + q0 + r) * S + k0 + k4];
            *(short4*)&W2[r * 72 + k4] = *(const short4*)&w16[(((size_t)hh * 2 + 1) * S + q0 + r) * S + k0 + k4];
        }
        #pragma unroll
        for (int it = 0; it < 8; ++it) {
            int lin = it * 256 + t;
            int dd = lin >> 4, k4 = (lin & 15) * 4;
            *(short4*)&Vc[dd * 72 + k4] = *(const short4*)&vpT[(size_t)(h * 128 + dd) * 1024 + k0 + k4];
        }
        __syncthreads();
        #pragma unroll
        for (int ks = 0; ks < 64; ks += 32) {
            f16x8 b[4];
            #pragma unroll
            for (int j = 0; j < 4; ++j)
                b[j] = *(const f16x8*)&Vc[(wn + j * 16 + fm) * 72 + ks + fq * 8];
            #pragma unroll
            for (int i = 0; i < 2; ++i) {
                int wo = (wm + i * 16 + fm) * 72 + ks + fq * 8;
                f16x8 w1f = *(const f16x8*)&W1[wo];
                f16x8 w2f = *(const f16x8*)&W2[wo];
                #pragma unroll
                for (int j = 0; j < 4; ++j) {
                    a1[i][j] = __builtin_amdgcn_mfma_f32_16x16x32_f16(w1f, b[j], a1[i][j], 0, 0, 0);
                    a2[i][j] = __builtin_amdgcn_mfma_f32_16x16x32_f16(w2f, b[j], a2[i][j], 0, 0, 0);
                }
            }
        }
    }
    #pragma unroll
    for (int i = 0; i < 2; ++i)
        #pragma unroll
        for (int j = 0; j < 4; ++j) {
            int d = wn + j * 16 + fm;
            #pragma unroll
            for (int reg = 0; reg < 4; ++reg) {
                int q = q0 + wm + i * 16 + fq * 4 + reg;
                size_t rowb = (size_t)(h * S + q) * 256;
                acat[rowb + d]       = a1[i][j][reg];
                acat[rowb + 128 + d] = a2[i][j][reg];
            }
        }
}

// ============================================================
// RMS over 256 complex + sub_w + (a1 - lam*a2) + complex gate (in place g).
// ============================================================
__global__ __launch_bounds__(256) void rmsgate_kernel(
    const float* __restrict__ acat_r, const float* __restrict__ acat_i,
    const float* __restrict__ sub_w, const float* __restrict__ lam_ptr,
    float* __restrict__ g_r, float* __restrict__ g_i)
{
    int row = blockIdx.x;
    int t = threadIdx.x;
    float ar = acat_r[(size_t)row * 256 + t];
    float ai = acat_i[(size_t)row * 256 + t];
    float ss = fmaf(ar, ar, ai * ai);
    #pragma unroll
    for (int off = 32; off; off >>= 1) ss += __shfl_xor(ss, off);
    __shared__ float red[4];
    if ((t & 63) == 0) red[t >> 6] = ss;
    __syncthreads();
    float total = red[0] + red[1] + red[2] + red[3];
    float inv_rms = 1.0f / sqrtf(total * (1.0f / 256.0f) + 1e-5f);
    float sw = sub_w[t];
    __shared__ float Cr[256], Ci[256];
    Cr[t] = ar * inv_rms * sw;
    Ci[t] = ai * inv_rms * sw;
    __syncthreads();
    if (t < 128) {
        float lam = lam_ptr[0];
        float o_r = Cr[t] - lam * Cr[t + 128];
        float o_i = Ci[t] - lam * Ci[t + 128];
        float gr = g_r[(size_t)row * 128 + t];
        float gi = g_i[(size_t)row * 128 + t];
        g_r[(size_t)row * 128 + t] = gr * o_r - gi * o_i;
        g_i[(size_t)row * 128 + t] = gr * o_i + gi * o_r;
    }
}

// ============================================================
extern "C" void kernel_launch(void* const* d_in, const int* in_sizes, int n_in,
                              void* d_out, int out_size, void* d_ws, size_t ws_size,
                              hipStream_t stream)
{
    (void)in_sizes; (void)n_in; (void)out_size;
    const float* q_r    = (const float*)d_in[0];
    const float* q_i    = (const float*)d_in[1];
    const float* k_r    = (const float*)d_in[2];
    const float* k_i    = (const float*)d_in[3];
    const float* v_r    = (const float*)d_in[4];
    const float* v_i    = (const float*)d_in[5];
    const float* pe_q_r = (const float*)d_in[6];
    const float* pe_q_i = (const float*)d_in[7];
    const float* pe_k_r = (const float*)d_in[8];
    const float* pe_k_i = (const float*)d_in[9];
    const float* qw_r   = (const float*)d_in[10];
    const float* qw_i   = (const float*)d_in[11];
    const float* qb_r   = (const float*)d_in[12];
    const float* qb_i   = (const float*)d_in[13];
    const float* kw_r   = (const float*)d_in[14];
    const float* kw_i   = (const float*)d_in[15];
    const float* kb_r   = (const float*)d_in[16];
    const float* kb_i   = (const float*)d_in[17];
    const float* vw_r   = (const float*)d_in[18];
    const float* vw_i   = (const float*)d_in[19];
    const float* vb_r   = (const float*)d_in[20];
    const float* vb_i   = (const float*)d_in[21];
    const float* gw_r   = (const float*)d_in[22];
    const float* gw_i   = (const float*)d_in[23];
    const float* gb_r   = (const float*)d_in[24];
    const float* gb_i   = (const float*)d_in[25];
    const float* ow_r   = (const float*)d_in[26];
    const float* ow_i   = (const float*)d_in[27];
    const float* ob_r   = (const float*)d_in[28];
    const float* ob_i   = (const float*)d_in[29];
    const float* lq1    = (const float*)d_in[30];
    const float* lk1    = (const float*)d_in[31];
    const float* lq2    = (const float*)d_in[32];
    const float* lk2    = (const float*)d_in[33];
    const float* sub_w  = (const float*)d_in[34];

    char* ws = (char*)d_ws;
    short* qp_r   = (short*)(ws + WS_QP_R);
    short* qp_i   = (short*)(ws + WS_QP_I);
    short* kp_r   = (short*)(ws + WS_KP_R);
    short* kp_i   = (short*)(ws + WS_KP_I);
    short* vpT_r  = (short*)(ws + WS_VPT_R);
    short* vpT_i  = (short*)(ws + WS_VPT_I);
    float* g_r    = (float*)(ws + WS_G_R);
    float* g_i    = (float*)(ws + WS_G_I);
    float* acat_r = (float*)(ws + WS_ACAT_R);
    float* acat_i = (float*)(ws + WS_ACAT_I);
    float* lam    = (float*)(ws + WS_LAM);
    short* w16    = (short*)(ws + WS_SC);

    float* out_r = (float*)d_out;
    float* out_i = out_r + (size_t)NROWS * D;

    // head-chunking by workspace (depends only on ws_size -> graph-safe)
    size_t avail = ws_size > WS_SC ? ws_size - WS_SC : 0;
    int nh_chunk = (int)(avail / W16_PER_HEAD);
    if (nh_chunk < 1) nh_chunk = 1;
    if (nh_chunk > H) nh_chunk = H;

    lam_kernel<<<1, 128, 0, stream>>>(lq1, lk1, lq2, lk2, lam);

    // ALL projections in one dispatch (q/k -> fp16 +PE; v -> fp16 T; g -> fp32)
    proj_all<<<dim3(96, 10), 256, 0, stream>>>(
        q_r, q_i, k_r, k_i, v_r, v_i, pe_q_r, pe_q_i, pe_k_r, pe_k_i,
        qw_r, qw_i, qb_r, qb_i, kw_r, kw_i, kb_r, kb_i,
        vw_r, vw_i, vb_r, vb_i, gw_r, gw_i, gb_r, gb_i,
        qp_r, qp_i, kp_r, kp_i, vpT_r, vpT_i, g_r, g_i);

    for (int h0 = 0; h0 < H; h0 += nh_chunk) {
        int nhh = (H - h0 < nh_chunk) ? (H - h0) : nh_chunk;
        score_mfma<<<dim3(16, 8, nhh * 2), 256, 0, stream>>>(qp_r, qp_i, kp_r, kp_i, w16, h0);
        softmax_f16<<<nhh * 2 * S, 256, 0, stream>>>(w16);
        av_mfma<<<dim3(16, 2, nhh), 256, 0, stream>>>(w16, vpT_r, vpT_i, acat_r, acat_i, h0);
    }

    rmsgate_kernel<<<NROWS, 256, 0, stream>>>(acat_r, acat_i, sub_w, lam, g_r, g_i);

    oproj_mfma<<<dim3(96, 2), 256, 0, stream>>>(g_r, g_i, ow_r, ow_i, ob_r, ob_i, out_r, out_i);
}

// Round 7
// 294.410 us; speedup vs baseline: 1.1856x; 1.0811x over previous
//
#include <hip/hip_runtime.h>
#include <math.h>

#define H 12
#define S 1024
#define D 128
#define NROWS (H * S) // 12288

typedef __attribute__((ext_vector_type(8))) _Float16 f16x8; // 8 fp16 in 4 VGPRs
typedef __attribute__((ext_vector_type(4))) float f32x4;
typedef __attribute__((ext_vector_type(4))) int i32x4;

__device__ __forceinline__ short f2h(float f) { // RNE float->fp16, bits as short
    _Float16 h = (_Float16)f;
    return __builtin_bit_cast(short, h);
}
__device__ __forceinline__ float h2f(short s) {
    return (float)__builtin_bit_cast(_Float16, s);
}
__device__ __forceinline__ f16x8 fneg8(f16x8 v) { // packed sign flip
    i32x4 u = __builtin_bit_cast(i32x4, v);
    u ^= (int)0x80008000;
    return __builtin_bit_cast(f16x8, u);
}

// ---- workspace layout (BYTE offsets) ----
// qp fp16 [12288][256] r/i ; kp fp16 [12288][128] r/i ; vpT fp16 [H][128][1024] r/i
// gp fp16 [12288][128] r/i ; acat fp16 [12288][256] r/i ; lam ;
// w16 fp16 per chunk-head 2*S*S ; stats float2 per chunk-head 2*S
#define WS_QP_R   0ULL
#define WS_QP_I   6291456ULL
#define WS_KP_R   12582912ULL
#define WS_KP_I   15728640ULL
#define WS_VPT_R  18874368ULL
#define WS_VPT_I  22020096ULL
#define WS_GP_R   25165824ULL
#define WS_GP_I   28311552ULL
#define WS_ACAT_R 31457280ULL
#define WS_ACAT_I 37748736ULL
#define WS_LAM    44040192ULL
#define WS_SC     44040448ULL
#define W16_PER_HEAD   4194304ULL // 2*1024*1024*2B
#define STAT_PER_HEAD  16384ULL   // 2*1024*8B

// ============================================================
__global__ void lam_kernel(const float* __restrict__ lq1, const float* __restrict__ lk1,
                           const float* __restrict__ lq2, const float* __restrict__ lk2,
                           float* __restrict__ lam_out)
{
    int t = threadIdx.x; // 128 threads
    float p1 = lq1[t] * lk1[t];
    float p2 = lq2[t] * lk2[t];
    #pragma unroll
    for (int off = 32; off; off >>= 1) {
        p1 += __shfl_xor(p1, off);
        p2 += __shfl_xor(p2, off);
    }
    __shared__ float s1[2], s2[2];
    if ((t & 63) == 0) { s1[t >> 6] = p1; s2[t >> 6] = p2; }
    __syncthreads();
    if (t == 0) {
        float l1 = expf(s1[0] + s1[1]);
        float l2 = expf(s2[0] + s2[1]);
        float x = l1 - l2 + 0.3555090675909693f; // 0.8 - 0.6*exp(-0.3)
        lam_out[0] = 1.0f / (1.0f + expf(-x));
    }
}

// ============================================================
// ALL FOUR projections in ONE dispatch. grid = (192, 10), 64x64 tiles:
//  y 0-3: q-proj  (M=256, fp16 out, +pe_q)       col0 = y*64
//  y 4-5: k-proj  (M=128, fp16 out, +pe_k)       col0 = (y-4)*64
//  y 6-7: v-proj  (M=128, fp16 transposed out)   col0 = (y-6)*64
//  y 8-9: g-proj  (M=128, fp16 out)              col0 = (y-8)*64
// K-concat 256: out_r = [xr,xi].[wr,-wi]^T ; out_i = [xr,xi].[wi,wr]^T
// 27.6KB LDS, 1920 blocks -> ~7.5 blocks/CU for latency hiding.
// ============================================================
__global__ __launch_bounds__(256) void proj_all(
    const float* __restrict__ q_r, const float* __restrict__ q_i,
    const float* __restrict__ k_r, const float* __restrict__ k_i,
    const float* __restrict__ v_r, const float* __restrict__ v_i,
    const float* __restrict__ pe_q_r, const float* __restrict__ pe_q_i,
    const float* __restrict__ pe_k_r, const float* __restrict__ pe_k_i,
    const float* __restrict__ qw_r, const float* __restrict__ qw_i,
    const float* __restrict__ qb_r, const float* __restrict__ qb_i,
    const float* __restrict__ kw_r, const float* __restrict__ kw_i,
    const float* __restrict__ kb_r, const float* __restrict__ kb_i,
    const float* __restrict__ vw_r, const float* __restrict__ vw_i,
    const float* __restrict__ vb_r, const float* __restrict__ vb_i,
    const float* __restrict__ gw_r, const float* __restrict__ gw_i,
    const float* __restrict__ gb_r, const float* __restrict__ gb_i,
    short* __restrict__ qp_r, short* __restrict__ qp_i,
    short* __restrict__ kp_r, short* __restrict__ kp_i,
    short* __restrict__ vpT_r, short* __restrict__ vpT_i,
    short* __restrict__ gp_r, short* __restrict__ gp_i)
{
    const int y = blockIdx.y;
    const float *xr, *xi, *wr, *wi, *br, *bi, *per = nullptr, *pei = nullptr;
    short *outr_, *outi_;
    int M, omode, col0;
    if (y < 4)      { xr = q_r; xi = q_i; wr = qw_r; wi = qw_i; br = qb_r; bi = qb_i;
                      per = pe_q_r; pei = pe_q_i; outr_ = qp_r; outi_ = qp_i;
                      M = 256; omode = 1; col0 = y * 64; }
    else if (y < 6) { xr = k_r; xi = k_i; wr = kw_r; wi = kw_i; br = kb_r; bi = kb_i;
                      per = pe_k_r; pei = pe_k_i; outr_ = kp_r; outi_ = kp_i;
                      M = 128; omode = 1; col0 = (y - 4) * 64; }
    else if (y < 8) { xr = v_r; xi = v_i; wr = vw_r; wi = vw_i; br = vb_r; bi = vb_i;
                      outr_ = vpT_r; outi_ = vpT_i;
                      M = 128; omode = 2; col0 = (y - 6) * 64; }
    else            { xr = q_r; xi = q_i; wr = gw_r; wi = gw_i; br = gb_r; bi = gb_i;
                      outr_ = gp_r; outi_ = gp_i;
                      M = 128; omode = 1; col0 = (y - 8) * 64; }

    __shared__ short As[64 * 72], Brs[64 * 72], Bis[64 * 72];
    const int t = threadIdx.x;
    const int row0 = blockIdx.x * 64;
    const int lane = t & 63, wid = t >> 6;
    const int wm = (wid >> 1) * 32, wn = (wid & 1) * 32;
    const int fm = lane & 15, fq = lane >> 4;
    f32x4 zero4 = {0.f, 0.f, 0.f, 0.f};
    f32x4 accr[2][2], acci[2][2];
    #pragma unroll
    for (int i = 0; i < 2; ++i)
        #pragma unroll
        for (int j = 0; j < 2; ++j) { accr[i][j] = zero4; acci[i][j] = zero4; }

    for (int c = 0; c < 4; ++c) {
        const bool hi = (c >= 2);
        const int kb = (c & 1) * 64;
        const float* Asrc = hi ? xi : xr;
        const float* Brsrc = hi ? wi : wr;
        const float* Bisrc = hi ? wr : wi;
        const float bsign = hi ? -1.0f : 1.0f;
        __syncthreads();
        #pragma unroll
        for (int it = 0; it < 4; ++it) {
            int lin = it * 256 + t;
            int r = lin >> 4, k4 = (lin & 15) * 4;
            float4 va = *(const float4*)&Asrc[(size_t)(row0 + r) * 128 + kb + k4];
            *(short4*)&As[r * 72 + k4] = make_short4(f2h(va.x), f2h(va.y), f2h(va.z), f2h(va.w));
            float4 vr = *(const float4*)&Brsrc[(size_t)(col0 + r) * 128 + kb + k4];
            *(short4*)&Brs[r * 72 + k4] = make_short4(f2h(bsign * vr.x), f2h(bsign * vr.y),
                                                      f2h(bsign * vr.z), f2h(bsign * vr.w));
            float4 vi = *(const float4*)&Bisrc[(size_t)(col0 + r) * 128 + kb + k4];
            *(short4*)&Bis[r * 72 + k4] = make_short4(f2h(vi.x), f2h(vi.y), f2h(vi.z), f2h(vi.w));
        }
        __syncthreads();
        #pragma unroll
        for (int ks = 0; ks < 64; ks += 32) {
            f16x8 bfr[2], bfi[2];
            #pragma unroll
            for (int j = 0; j < 2; ++j) {
                bfr[j] = *(const f16x8*)&Brs[(wn + j * 16 + fm) * 72 + ks + fq * 8];
                bfi[j] = *(const f16x8*)&Bis[(wn + j * 16 + fm) * 72 + ks + fq * 8];
            }
            #pragma unroll
            for (int i = 0; i < 2; ++i) {
                f16x8 a = *(const f16x8*)&As[(wm + i * 16 + fm) * 72 + ks + fq * 8];
                #pragma unroll
                for (int j = 0; j < 2; ++j) {
                    accr[i][j] = __builtin_amdgcn_mfma_f32_16x16x32_f16(a, bfr[j], accr[i][j], 0, 0, 0);
                    acci[i][j] = __builtin_amdgcn_mfma_f32_16x16x32_f16(a, bfi[j], acci[i][j], 0, 0, 0);
                }
            }
        }
    }
    #pragma unroll
    for (int i = 0; i < 2; ++i)
        #pragma unroll
        for (int j = 0; j < 2; ++j) {
            int colc = col0 + wn + j * 16 + fm;
            float bbr = br[colc], bbi = bi[colc];
            if (omode == 2) {
                int rb = row0 + wm + i * 16 + fq * 4;
                int hq = rb >> 10, sq = rb & 1023;
                short4 o_r4 = make_short4(f2h(accr[i][j][0] + bbr), f2h(accr[i][j][1] + bbr),
                                          f2h(accr[i][j][2] + bbr), f2h(accr[i][j][3] + bbr));
                short4 o_i4 = make_short4(f2h(acci[i][j][0] + bbi), f2h(acci[i][j][1] + bbi),
                                          f2h(acci[i][j][2] + bbi), f2h(acci[i][j][3] + bbi));
                size_t ob = ((size_t)(hq * 128 + colc)) * 1024 + sq;
                *(short4*)&outr_[ob] = o_r4;
                *(short4*)&outi_[ob] = o_i4;
            } else {
                #pragma unroll
                for (int reg = 0; reg < 4; ++reg) {
                    int rr = row0 + wm + i * 16 + fq * 4 + reg;
                    float o_r = accr[i][j][reg] + bbr;
                    float o_i = acci[i][j][reg] + bbi;
                    if (per) {
                        o_r += per[(size_t)rr * 128 + (colc & 127)];
                        o_i += pei[(size_t)rr * 128 + (colc & 127)];
                    }
                    outr_[(size_t)rr * M + colc] = f2h(o_r);
                    outi_[(size_t)rr * M + colc] = f2h(o_i);
                }
            }
        }
}

// ============================================================
// o-projection: fp16 gated input gp, fp32 weights, fp32 out. 64x64 tiles.
// ============================================================
__global__ __launch_bounds__(256) void oproj_mfma(
    const short* __restrict__ gp_r, const short* __restrict__ gp_i,
    const float* __restrict__ wr, const float* __restrict__ wi,
    const float* __restrict__ br, const float* __restrict__ bi,
    float* __restrict__ outr, float* __restrict__ outi)
{
    __shared__ short As[64 * 72], Brs[64 * 72], Bis[64 * 72];
    const int t = threadIdx.x;
    const int row0 = blockIdx.x * 64, col0 = blockIdx.y * 64;
    const int lane = t & 63, wid = t >> 6;
    const int wm = (wid >> 1) * 32, wn = (wid & 1) * 32;
    const int fm = lane & 15, fq = lane >> 4;
    f32x4 zero4 = {0.f, 0.f, 0.f, 0.f};
    f32x4 accr[2][2], acci[2][2];
    #pragma unroll
    for (int i = 0; i < 2; ++i)
        #pragma unroll
        for (int j = 0; j < 2; ++j) { accr[i][j] = zero4; acci[i][j] = zero4; }

    for (int c = 0; c < 4; ++c) {
        const bool hi = (c >= 2);
        const int kb = (c & 1) * 64;
        const short* Asrc = hi ? gp_i : gp_r;
        const float* Brsrc = hi ? wi : wr;
        const float* Bisrc = hi ? wr : wi;
        const float bsign = hi ? -1.0f : 1.0f;
        __syncthreads();
        #pragma unroll
        for (int it = 0; it < 4; ++it) {
            int lin = it * 256 + t;
            int r = lin >> 4, k4 = (lin & 15) * 4;
            *(short4*)&As[r * 72 + k4] = *(const short4*)&Asrc[(size_t)(row0 + r) * 128 + kb + k4];
            float4 vr = *(const float4*)&Brsrc[(size_t)(col0 + r) * 128 + kb + k4];
            *(short4*)&Brs[r * 72 + k4] = make_short4(f2h(bsign * vr.x), f2h(bsign * vr.y),
                                                      f2h(bsign * vr.z), f2h(bsign * vr.w));
            float4 vi = *(const float4*)&Bisrc[(size_t)(col0 + r) * 128 + kb + k4];
            *(short4*)&Bis[r * 72 + k4] = make_short4(f2h(vi.x), f2h(vi.y), f2h(vi.z), f2h(vi.w));
        }
        __syncthreads();
        #pragma unroll
        for (int ks = 0; ks < 64; ks += 32) {
            f16x8 bfr[2], bfi[2];
            #pragma unroll
            for (int j = 0; j < 2; ++j) {
                bfr[j] = *(const f16x8*)&Brs[(wn + j * 16 + fm) * 72 + ks + fq * 8];
                bfi[j] = *(const f16x8*)&Bis[(wn + j * 16 + fm) * 72 + ks + fq * 8];
            }
            #pragma unroll
            for (int i = 0; i < 2; ++i) {
                f16x8 a = *(const f16x8*)&As[(wm + i * 16 + fm) * 72 + ks + fq * 8];
                #pragma unroll
                for (int j = 0; j < 2; ++j) {
                    accr[i][j] = __builtin_amdgcn_mfma_f32_16x16x32_f16(a, bfr[j], accr[i][j], 0, 0, 0);
                    acci[i][j] = __builtin_amdgcn_mfma_f32_16x16x32_f16(a, bfi[j], acci[i][j], 0, 0, 0);
                }
            }
        }
    }
    #pragma unroll
    for (int i = 0; i < 2; ++i)
        #pragma unroll
        for (int j = 0; j < 2; ++j) {
            int colc = col0 + wn + j * 16 + fm;
            float bbr = br[colc], bbi = bi[colc];
            #pragma unroll
            for (int reg = 0; reg < 4; ++reg) {
                int rr = row0 + wm + i * 16 + fq * 4 + reg;
                outr[(size_t)rr * 128 + colc] = accr[i][j][reg] + bbr;
                outi[(size_t)rr * 128 + colc] = acci[i][j][reg] + bbi;
            }
        }
}

// ============================================================
// Scores (proven r4 config): one map per block, 64q x 128k tile, K-chunk 64.
// A-fragments held in regs across two B-phases (kr, then ki):
//   phase1: sr += qr.kr ; si += qi.kr
//   phase2: sr += qi.ki ; si += (-qr).ki
// mag -> fp16 w16[(hh*2+map)*S+q][k]. 36KB LDS, ~108 VGPR.
// ============================================================
__global__ __launch_bounds__(256) void score_mfma(
    const short* __restrict__ qp_r, const short* __restrict__ qp_i,
    const short* __restrict__ kp_r, const short* __restrict__ kp_i,
    short* __restrict__ w16, int h0)
{
    __shared__ short Qr[64 * 72], Qi[64 * 72], Kt[128 * 72];
    const int t = threadIdx.x;
    const int hh = blockIdx.z >> 1, map = blockIdx.z & 1;
    const int h = h0 + hh;
    const int q0 = blockIdx.x * 64, c0 = blockIdx.y * 128;
    const int lane = t & 63, wid = t >> 6;
    const int wm = (wid >> 1) * 32, wn = (wid & 1) * 64;
    const int fm = lane & 15, fq = lane >> 4;
    f32x4 zero4 = {0.f, 0.f, 0.f, 0.f};
    f32x4 sr[2][4], si[2][4];
    #pragma unroll
    for (int i = 0; i < 2; ++i)
        #pragma unroll
        for (int j = 0; j < 4; ++j) { sr[i][j] = zero4; si[i][j] = zero4; }

    for (int kb = 0; kb < 2; ++kb) {
        const int kbase = map * 128 + kb * 64;
        __syncthreads();
        #pragma unroll
        for (int i = 0; i < 4; ++i) {
            int lin = i * 256 + t;
            int r = lin >> 4, k4 = (lin & 15) * 4;
            size_t qb = (size_t)(h * S + q0 + r) * 256 + kbase + k4;
            *(short4*)&Qr[r * 72 + k4] = *(const short4*)&qp_r[qb];
            *(short4*)&Qi[r * 72 + k4] = *(const short4*)&qp_i[qb];
        }
        #pragma unroll
        for (int i = 0; i < 8; ++i) {
            int lin = i * 256 + t;
            int r = lin >> 4, k4 = (lin & 15) * 4;
            *(short4*)&Kt[r * 72 + k4] =
                *(const short4*)&kp_r[(size_t)(h * S + c0 + r) * 128 + kb * 64 + k4];
        }
        __syncthreads();
        f16x8 aR[2][2], aI[2][2]; // [ks][i]
        #pragma unroll
        for (int ks = 0; ks < 2; ++ks)
            #pragma unroll
            for (int i = 0; i < 2; ++i) {
                int ao = (wm + i * 16 + fm) * 72 + ks * 32 + fq * 8;
                aR[ks][i] = *(const f16x8*)&Qr[ao];
                aI[ks][i] = *(const f16x8*)&Qi[ao];
            }
        #pragma unroll
        for (int ks = 0; ks < 2; ++ks) {
            f16x8 b[4];
            #pragma unroll
            for (int j = 0; j < 4; ++j)
                b[j] = *(const f16x8*)&Kt[(wn + j * 16 + fm) * 72 + ks * 32 + fq * 8];
            #pragma unroll
            for (int i = 0; i < 2; ++i)
                #pragma unroll
                for (int j = 0; j < 4; ++j) {
                    sr[i][j] = __builtin_amdgcn_mfma_f32_16x16x32_f16(aR[ks][i], b[j], sr[i][j], 0, 0, 0);
                    si[i][j] = __builtin_amdgcn_mfma_f32_16x16x32_f16(aI[ks][i], b[j], si[i][j], 0, 0, 0);
                }
        }
        __syncthreads();
        #pragma unroll
        for (int i = 0; i < 8; ++i) {
            int lin = i * 256 + t;
            int r = lin >> 4, k4 = (lin & 15) * 4;
            *(short4*)&Kt[r * 72 + k4] =
                *(const short4*)&kp_i[(size_t)(h * S + c0 + r) * 128 + kb * 64 + k4];
        }
        __syncthreads();
        #pragma unroll
        for (int ks = 0; ks < 2; ++ks) {
            f16x8 b[4];
            #pragma unroll
            for (int j = 0; j < 4; ++j)
                b[j] = *(const f16x8*)&Kt[(wn + j * 16 + fm) * 72 + ks * 32 + fq * 8];
            f16x8 nR0 = fneg8(aR[ks][0]), nR1 = fneg8(aR[ks][1]);
            #pragma unroll
            for (int j = 0; j < 4; ++j) {
                sr[0][j] = __builtin_amdgcn_mfma_f32_16x16x32_f16(aI[ks][0], b[j], sr[0][j], 0, 0, 0);
                si[0][j] = __builtin_amdgcn_mfma_f32_16x16x32_f16(nR0, b[j], si[0][j], 0, 0, 0);
                sr[1][j] = __builtin_amdgcn_mfma_f32_16x16x32_f16(aI[ks][1], b[j], sr[1][j], 0, 0, 0);
                si[1][j] = __builtin_amdgcn_mfma_f32_16x16x32_f16(nR1, b[j], si[1][j], 0, 0, 0);
            }
        }
    }
    const float scale = 0.08838834764831845f;
    #pragma unroll
    for (int i = 0; i < 2; ++i)
        #pragma unroll
        for (int j = 0; j < 4; ++j) {
            int kcol = c0 + wn + j * 16 + fm;
            #pragma unroll
            for (int reg = 0; reg < 4; ++reg) {
                int q = q0 + wm + i * 16 + fq * 4 + reg;
                float r1 = sr[i][j][reg], I1 = si[i][j][reg];
                float m1 = sqrtf(fmaf(r1, r1, fmaf(I1, I1, 1e-8f))) * scale;
                w16[(((size_t)hh * 2 + map) * S + q) * S + kcol] = f2h(m1);
            }
        }
}

// ============================================================
// Per-row softmax STATS only (read-only over mags): stats[row]=(max, 1/sum).
// av applies exp((m-max))*inv_sum on the fly -> kills the 50MB softmax RMW.
// ============================================================
__global__ __launch_bounds__(256) void smstats(const short* __restrict__ w16,
                                               float2* __restrict__ stats)
{
    const short* row = w16 + (size_t)blockIdx.x * S;
    int t = threadIdx.x;
    short4 s = ((const short4*)row)[t];
    float f0 = h2f(s.x), f1 = h2f(s.y), f2v = h2f(s.z), f3 = h2f(s.w);
    float m = fmaxf(fmaxf(f0, f1), fmaxf(f2v, f3));
    #pragma unroll
    for (int off = 32; off; off >>= 1) m = fmaxf(m, __shfl_xor(m, off));
    __shared__ float redm[4], reds[4];
    int w = t >> 6;
    if ((t & 63) == 0) redm[w] = m;
    __syncthreads();
    m = fmaxf(fmaxf(redm[0], redm[1]), fmaxf(redm[2], redm[3]));
    float ssum = __expf(f0 - m) + __expf(f1 - m) + __expf(f2v - m) + __expf(f3 - m);
    #pragma unroll
    for (int off = 32; off; off >>= 1) ssum += __shfl_xor(ssum, off);
    if ((t & 63) == 0) reds[w] = ssum;
    __syncthreads();
    if (t == 0) {
        float total = reds[0] + reds[1] + reds[2] + reds[3];
        stats[blockIdx.x] = make_float2(m, 1.0f / total);
    }
}

// ============================================================
// AV: 32q x full 128d, both maps, ONE complex comp per block (blockIdx.y).
// W tiles = exp(mag - max)*inv_sum computed at staging. V from vpT[h][d][s].
// acat out fp16. 27.6KB LDS, grid 768 -> 5 blocks/CU.
// ============================================================
__global__ __launch_bounds__(256) void av_mfma(
    const short* __restrict__ w16, const float2* __restrict__ stats,
    const short* __restrict__ vpT_r, const short* __restrict__ vpT_i,
    short* __restrict__ acat_r, short* __restrict__ acat_i, int h0)
{
    __shared__ short W1[32 * 72], W2[32 * 72], Vc[128 * 72];
    const int t = threadIdx.x;
    const int hh = blockIdx.z, h = h0 + hh;
    const int comp = blockIdx.y;
    const int q0 = blockIdx.x * 32;
    const short* vpT = comp ? vpT_i : vpT_r;
    short* acat = comp ? acat_i : acat_r;
    const float2* st1 = stats + ((size_t)hh * 2 + 0) * S;
    const float2* st2 = stats + ((size_t)hh * 2 + 1) * S;
    const int lane = t & 63, wid = t >> 6;
    const int wm = (wid >> 1) * 16, wn = (wid & 1) * 64;
    const int fm = lane & 15, fq = lane >> 4;
    f32x4 zero4 = {0.f, 0.f, 0.f, 0.f};
    f32x4 a1[4], a2[4];
    #pragma unroll
    for (int j = 0; j < 4; ++j) { a1[j] = zero4; a2[j] = zero4; }

    for (int k0 = 0; k0 < S; k0 += 64) {
        __syncthreads();
        #pragma unroll
        for (int it = 0; it < 2; ++it) {
            int lin = it * 256 + t;
            int r = lin >> 4, k4 = (lin & 15) * 4;
            float2 s1v = st1[q0 + r];
            float2 s2v = st2[q0 + r];
            short4 m1 = *(const short4*)&w16[(((size_t)hh * 2 + 0) * S + q0 + r) * S + k0 + k4];
            short4 m2 = *(const short4*)&w16[(((size_t)hh * 2 + 1) * S + q0 + r) * S + k0 + k4];
            *(short4*)&W1[r * 72 + k4] = make_short4(
                f2h(__expf(h2f(m1.x) - s1v.x) * s1v.y), f2h(__expf(h2f(m1.y) - s1v.x) * s1v.y),
                f2h(__expf(h2f(m1.z) - s1v.x) * s1v.y), f2h(__expf(h2f(m1.w) - s1v.x) * s1v.y));
            *(short4*)&W2[r * 72 + k4] = make_short4(
                f2h(__expf(h2f(m2.x) - s2v.x) * s2v.y), f2h(__expf(h2f(m2.y) - s2v.x) * s2v.y),
                f2h(__expf(h2f(m2.z) - s2v.x) * s2v.y), f2h(__expf(h2f(m2.w) - s2v.x) * s2v.y));
        }
        #pragma unroll
        for (int it = 0; it < 8; ++it) {
            int lin = it * 256 + t;
            int dd = lin >> 4, k4 = (lin & 15) * 4;
            *(short4*)&Vc[dd * 72 + k4] = *(const short4*)&vpT[(size_t)(h * 128 + dd) * 1024 + k0 + k4];
        }
        __syncthreads();
        #pragma unroll
        for (int ks = 0; ks < 64; ks += 32) {
            f16x8 b[4];
            #pragma unroll
            for (int j = 0; j < 4; ++j)
                b[j] = *(const f16x8*)&Vc[(wn + j * 16 + fm) * 72 + ks + fq * 8];
            int wo = (wm + fm) * 72 + ks + fq * 8;
            f16x8 w1f = *(const f16x8*)&W1[wo];
            f16x8 w2f = *(const f16x8*)&W2[wo];
            #pragma unroll
            for (int j = 0; j < 4; ++j) {
                a1[j] = __builtin_amdgcn_mfma_f32_16x16x32_f16(w1f, b[j], a1[j], 0, 0, 0);
                a2[j] = __builtin_amdgcn_mfma_f32_16x16x32_f16(w2f, b[j], a2[j], 0, 0, 0);
            }
        }
    }
    #pragma unroll
    for (int j = 0; j < 4; ++j) {
        int d = wn + j * 16 + fm;
        #pragma unroll
        for (int reg = 0; reg < 4; ++reg) {
            int q = q0 + wm + fq * 4 + reg;
            size_t rowb = (size_t)(h * S + q) * 256;
            acat[rowb + d]       = f2h(a1[j][reg]);
            acat[rowb + 128 + d] = f2h(a2[j][reg]);
        }
    }
}

// ============================================================
// RMS over 256 complex + sub_w + (a1 - lam*a2) + complex gate.
// acat fp16 in, gp fp16 in/out (in place).
// ============================================================
__global__ __launch_bounds__(256) void rmsgate_kernel(
    const short* __restrict__ acat_r, const short* __restrict__ acat_i,
    const float* __restrict__ sub_w, const float* __restrict__ lam_ptr,
    short* __restrict__ gp_r, short* __restrict__ gp_i)
{
    int row = blockIdx.x;
    int t = threadIdx.x;
    float ar = h2f(acat_r[(size_t)row * 256 + t]);
    float ai = h2f(acat_i[(size_t)row * 256 + t]);
    float ss = fmaf(ar, ar, ai * ai);
    #pragma unroll
    for (int off = 32; off; off >>= 1) ss += __shfl_xor(ss, off);
    __shared__ float red[4];
    if ((t & 63) == 0) red[t >> 6] = ss;
    __syncthreads();
    float total = red[0] + red[1] + red[2] + red[3];
    float inv_rms = 1.0f / sqrtf(total * (1.0f / 256.0f) + 1e-5f);
    float sw = sub_w[t];
    __shared__ float Cr[256], Ci[256];
    Cr[t] = ar * inv_rms * sw;
    Ci[t] = ai * inv_rms * sw;
    __syncthreads();
    if (t < 128) {
        float lam = lam_ptr[0];
        float o_r = Cr[t] - lam * Cr[t + 128];
        float o_i = Ci[t] - lam * Ci[t + 128];
        float gr = h2f(gp_r[(size_t)row * 128 + t]);
        float gi = h2f(gp_i[(size_t)row * 128 + t]);
        gp_r[(size_t)row * 128 + t] = f2h(gr * o_r - gi * o_i);
        gp_i[(size_t)row * 128 + t] = f2h(gr * o_i + gi * o_r);
    }
}

// ============================================================
extern "C" void kernel_launch(void* const* d_in, const int* in_sizes, int n_in,
                              void* d_out, int out_size, void* d_ws, size_t ws_size,
                              hipStream_t stream)
{
    (void)in_sizes; (void)n_in; (void)out_size;
    const float* q_r    = (const float*)d_in[0];
    const float* q_i    = (const float*)d_in[1];
    const float* k_r    = (const float*)d_in[2];
    const float* k_i    = (const float*)d_in[3];
    const float* v_r    = (const float*)d_in[4];
    const float* v_i    = (const float*)d_in[5];
    const float* pe_q_r = (const float*)d_in[6];
    const float* pe_q_i = (const float*)d_in[7];
    const float* pe_k_r = (const float*)d_in[8];
    const float* pe_k_i = (const float*)d_in[9];
    const float* qw_r   = (const float*)d_in[10];
    const float* qw_i   = (const float*)d_in[11];
    const float* qb_r   = (const float*)d_in[12];
    const float* qb_i   = (const float*)d_in[13];
    const float* kw_r   = (const float*)d_in[14];
    const float* kw_i   = (const float*)d_in[15];
    const float* kb_r   = (const float*)d_in[16];
    const float* kb_i   = (const float*)d_in[17];
    const float* vw_r   = (const float*)d_in[18];
    const float* vw_i   = (const float*)d_in[19];
    const float* vb_r   = (const float*)d_in[20];
    const float* vb_i   = (const float*)d_in[21];
    const float* gw_r   = (const float*)d_in[22];
    const float* gw_i   = (const float*)d_in[23];
    const float* gb_r   = (const float*)d_in[24];
    const float* gb_i   = (const float*)d_in[25];
    const float* ow_r   = (const float*)d_in[26];
    const float* ow_i   = (const float*)d_in[27];
    const float* ob_r   = (const float*)d_in[28];
    const float* ob_i   = (const float*)d_in[29];
    const float* lq1    = (const float*)d_in[30];
    const float* lk1    = (const float*)d_in[31];
    const float* lq2    = (const float*)d_in[32];
    const float* lk2    = (const float*)d_in[33];
    const float* sub_w  = (const float*)d_in[34];

    char* ws = (char*)d_ws;
    short* qp_r   = (short*)(ws + WS_QP_R);
    short* qp_i   = (short*)(ws + WS_QP_I);
    short* kp_r   = (short*)(ws + WS_KP_R);
    short* kp_i   = (short*)(ws + WS_KP_I);
    short* vpT_r  = (short*)(ws + WS_VPT_R);
    short* vpT_i  = (short*)(ws + WS_VPT_I);
    short* gp_r   = (short*)(ws + WS_GP_R);
    short* gp_i   = (short*)(ws + WS_GP_I);
    short* acat_r = (short*)(ws + WS_ACAT_R);
    short* acat_i = (short*)(ws + WS_ACAT_I);
    float* lam    = (float*)(ws + WS_LAM);
    short* w16    = (short*)(ws + WS_SC);

    float* out_r = (float*)d_out;
    float* out_i = out_r + (size_t)NROWS * D;

    // head-chunking by workspace (depends only on ws_size -> graph-safe)
    size_t avail = ws_size > WS_SC ? ws_size - WS_SC : 0;
    int nh_chunk = (int)(avail / (W16_PER_HEAD + STAT_PER_HEAD));
    if (nh_chunk < 1) nh_chunk = 1;
    if (nh_chunk > H) nh_chunk = H;
    float2* stats = (float2*)(ws + WS_SC + (size_t)nh_chunk * W16_PER_HEAD);

    lam_kernel<<<1, 128, 0, stream>>>(lq1, lk1, lq2, lk2, lam);

    // ALL projections in one dispatch (q/k -> fp16 +PE; v -> fp16 T; g -> fp16)
    proj_all<<<dim3(192, 10), 256, 0, stream>>>(
        q_r, q_i, k_r, k_i, v_r, v_i, pe_q_r, pe_q_i, pe_k_r, pe_k_i,
        qw_r, qw_i, qb_r, qb_i, kw_r, kw_i, kb_r, kb_i,
        vw_r, vw_i, vb_r, vb_i, gw_r, gw_i, gb_r, gb_i,
        qp_r, qp_i, kp_r, kp_i, vpT_r, vpT_i, gp_r, gp_i);

    for (int h0 = 0; h0 < H; h0 += nh_chunk) {
        int nhh = (H - h0 < nh_chunk) ? (H - h0) : nh_chunk;
        score_mfma<<<dim3(16, 8, nhh * 2), 256, 0, stream>>>(qp_r, qp_i, kp_r, kp_i, w16, h0);
        smstats<<<nhh * 2 * S, 256, 0, stream>>>(w16, stats);
        av_mfma<<<dim3(32, 2, nhh), 256, 0, stream>>>(w16, stats, vpT_r, vpT_i, acat_r, acat_i, h0);
    }

    rmsgate_kernel<<<NROWS, 256, 0, stream>>>(acat_r, acat_i, sub_w, lam, gp_r, gp_i);

    oproj_mfma<<<dim3(192, 2), 256, 0, stream>>>(gp_r, gp_i, ow_r, ow_i, ob_r, ob_i, out_r, out_i);
}